// Round 16
// baseline (6776.259 us; speedup 1.0000x reference)
//
#include <hip/hip_runtime.h>

#define N_PTS 16384
#define ROWF  131        // 3 coords + 128 features
#define M_OUT 4096       // N / POOL
#define KNN   16
#define FPS_T 1024       // fps threads (16 waves)
#define SORT_T 1024

typedef unsigned long long u64;
typedef float f32x2 __attribute__((ext_vector_type(2)));

// spread 4 bits -> every 3rd bit (Morton interleave LUT)
__device__ __constant__ unsigned short c_spread4[16] =
  {0,1,8,9,64,65,72,73,512,513,520,521,576,577,584,585};

__device__ __forceinline__ int cell_of(float x, float y, float z) {
  int ix = (int)floorf((x + 4.0f) * 2.0f); ix = ix < 0 ? 0 : (ix > 15 ? 15 : ix);
  int iy = (int)floorf((y + 4.0f) * 2.0f); iy = iy < 0 ? 0 : (iy > 15 ? 15 : iy);
  int iz = (int)floorf((z + 4.0f) * 2.0f); iz = iz < 0 ? 0 : (iz > 15 ? 15 : iz);
  return (int)c_spread4[ix] | ((int)c_spread4[iy] << 1) | ((int)c_spread4[iz] << 2);
}

// u64 max-combine with a DPP-moved partner (VALU pipe). Proven r10-r15.
template <int CTRL, int ROW_MASK>
__device__ __forceinline__ u64 kmax_dpp(u64 k) {
  const int lo = (int)(unsigned)k, hi = (int)(unsigned)(k >> 32);
  const int nlo = __builtin_amdgcn_update_dpp(lo, lo, CTRL, ROW_MASK, 0xf, false);
  const int nhi = __builtin_amdgcn_update_dpp(hi, hi, CTRL, ROW_MASK, 0xf, false);
  const u64 nk = ((u64)(unsigned)nhi << 32) | (unsigned)nlo;
  return nk > k ? nk : k;
}

// ---------------------------------------------------------------------------
// 1) Extract coords into packed float4 (x,y,z,0), original index order
//    (used by fps winner lookup and knn).
// ---------------------------------------------------------------------------
__global__ void prep_kernel(const float* __restrict__ x,
                            float4* __restrict__ coords4) {
  const int p = blockIdx.x * blockDim.x + threadIdx.x;
  if (p < N_PTS) {
    coords4[p] = make_float4(x[p * ROWF + 0], x[p * ROWF + 1],
                             x[p * ROWF + 2], 0.0f);
  }
}

// ---------------------------------------------------------------------------
// 2) Counting-sort by Morton cell (4096 cells), one 1024-thread block.
//    Output slot-major float4 (x,y,z,bitcast(origIdx)): sorted rank rk ->
//    slot ((rk&15)<<10)|(rk>>4), so fps thread t owns the 16 CONSECUTIVE
//    ranks [16t,16t+16) (spatially compact chunk) and its init loads
//    gP4[(j<<10)+t] are coalesced. Within-cell scatter order is racy but
//    output-invariant (downstream keyed by orig index; skips provable
//    no-ops). Proven r4-r11.
// ---------------------------------------------------------------------------
__global__ __launch_bounds__(1024, 1)
void sort_kernel(const float4* __restrict__ coords4, float4* __restrict__ gP4) {
  __shared__ unsigned int sh[4096];
  __shared__ unsigned int sws[16];
  const int tid = threadIdx.x, lane = tid & 63, wid = tid >> 6;

#pragma unroll
  for (int i = 0; i < 4; ++i) sh[tid * 4 + i] = 0;
  __syncthreads();

  int cel[16];
#pragma unroll
  for (int j = 0; j < 16; ++j) {
    const float4 v = coords4[tid + SORT_T * j];
    const int c = cell_of(v.x, v.y, v.z);
    cel[j] = c;
    atomicAdd(&sh[c], 1u);
  }
  __syncthreads();

  const unsigned h0 = sh[tid * 4 + 0], h1 = sh[tid * 4 + 1];
  const unsigned h2 = sh[tid * 4 + 2], h3 = sh[tid * 4 + 3];
  const unsigned tsum = h0 + h1 + h2 + h3;
  unsigned inc = tsum;
#pragma unroll
  for (int off = 1; off < 64; off <<= 1) {
    const unsigned v = __shfl_up(inc, off);
    if (lane >= off) inc += v;
  }
  if (lane == 63) sws[wid] = inc;
  __syncthreads();
  if (tid == 0) {
    unsigned run = 0;
#pragma unroll
    for (int w = 0; w < 16; ++w) { const unsigned t = sws[w]; sws[w] = run; run += t; }
  }
  __syncthreads();
  const unsigned base = sws[wid] + inc - tsum;
  sh[tid * 4 + 0] = base;
  sh[tid * 4 + 1] = base + h0;
  sh[tid * 4 + 2] = base + h0 + h1;
  sh[tid * 4 + 3] = base + h0 + h1 + h2;
  __syncthreads();

#pragma unroll
  for (int j = 0; j < 16; ++j) {
    const int p = tid + SORT_T * j;
    const float4 v = coords4[p];
    const unsigned rk = atomicAdd(&sh[cel[j]], 1u);
    const int slot = (int)(((rk & 15u) << 10) | (rk >> 4));
    gP4[slot] = make_float4(v.x, v.y, v.z, __int_as_float(p));
  }
}

// ---------------------------------------------------------------------------
// 3) FPS v14 = r15 lean structure + r9's proven ballot chunk-prune.
//    r15 post-mortem: issue ~1450 cyc/SIMD/step, tail ~2300 -> issue savings
//    now visible (r9's ballot measurably cut VALU 36% but was tail-masked).
//    Per-lane 16-pt chunk sphere (Morton-compact); wave runs the update iff
//    ANY lane dirty (__ballot). Skip => (conservative margins, proven
//    absmax=0 in r9/r11/r12) no member's fminf(md,d2) changes AND cached
//    wave key wkk stays valid. Winner's wave always dirty (dd<=cr^2<=thr).
//    Dirty path: pk-pair update (bitwise == scalar __fmul_rn/__fadd_rn
//    chain), max3-tree fold, min-orig-idx tie scan, 6-level DPP u64 wave
//    fold (lane63 -> parity LDS), ONE barrier, 4-level DPP block fold,
//    uniform winner load. Key=(md_bits<<32)|(16383-ni): max md, tie ->
//    lowest original index (exact numpy argmax semantics).
// ---------------------------------------------------------------------------
#define REP16(F) F(0) F(1) F(2) F(3) F(4) F(5) F(6) F(7) \
                 F(8) F(9) F(10) F(11) F(12) F(13) F(14) F(15)
#define REPP(F) F(0,0,1) F(1,2,3) F(2,4,5) F(3,6,7) \
                F(4,8,9) F(5,10,11) F(6,12,13) F(7,14,15)

__global__
__attribute__((amdgpu_flat_work_group_size(FPS_T, FPS_T)))
__attribute__((amdgpu_waves_per_eu(4, 4)))
void fps_kernel(const float4* __restrict__ coords4,
                const float4* __restrict__ gP4, float* __restrict__ out) {
#pragma clang fp contract(off)
  __shared__ u64 s_wkey[2][16];
  const int tid = threadIdx.x, lane = tid & 63, wid = tid >> 6;

#define FPS_DECL(t,a,b) f32x2 PX##t, PY##t, PZ##t; \
                        float md##a, md##b; unsigned ni##a, ni##b;
  REPP(FPS_DECL)
#undef FPS_DECL

#define FPS_INIT(t,a,b) {                                                  \
    const float4 va = gP4[(a << 10) + tid];                                \
    const float4 vb = gP4[(b << 10) + tid];                                \
    PX##t = (f32x2){va.x, vb.x};                                           \
    PY##t = (f32x2){va.y, vb.y};                                           \
    PZ##t = (f32x2){va.z, vb.z};                                           \
    ni##a = (unsigned)__float_as_int(va.w);                                \
    ni##b = (unsigned)__float_as_int(vb.w);                                \
    md##a = __int_as_float(0x7f800000);                                    \
    md##b = __int_as_float(0x7f800000); }
  REPP(FPS_INIT)
#undef FPS_INIT

  // per-lane chunk bounding sphere over this lane's 16 compact points
  float sx = 0.f, sy = 0.f, sz = 0.f;
#define FPS_ACC(t,a,b) { sx += PX##t.x + PX##t.y;                          \
    sy += PY##t.x + PY##t.y; sz += PZ##t.x + PZ##t.y; }
  REPP(FPS_ACC)
#undef FPS_ACC
  const float ccx = sx * (1.0f / 16.0f), ccy = sy * (1.0f / 16.0f),
              ccz = sz * (1.0f / 16.0f);
  float cr2 = 0.f;
#define FPS_RAD(t,a,b) {                                                   \
    { const float dx = PX##t.x - ccx, dy = PY##t.x - ccy,                  \
                  dz = PZ##t.x - ccz;                                      \
      cr2 = fmaxf(cr2, dx * dx + dy * dy + dz * dz); }                     \
    { const float dx = PX##t.y - ccx, dy = PY##t.y - ccy,                  \
                  dz = PZ##t.y - ccz;                                      \
      cr2 = fmaxf(cr2, dx * dx + dy * dy + dz * dz); } }
  REPP(FPS_RAD)
#undef FPS_RAD
  const float cr = sqrtf(cr2) * 1.000001f + 1e-6f;

  float thr = __int_as_float(0x7f800000);  // +inf => first step dirty
  u64 wkk = 0;                             // cached fold result (lane63 = wave max)

  const float4 q0 = coords4[0];
  float qx = q0.x, qy = q0.y, qz = q0.z;
  if (tid == 0) { out[0] = qx; out[1] = qy; out[2] = qz; }

  for (int s = 1; s < M_OUT; ++s) {
    // per-lane chunk prune test; wave updates iff ANY lane dirty
    const float dqx = qx - ccx, dqy = qy - ccy, dqz = qz - ccz;
    const float dd = dqx * dqx + dqy * dqy + dqz * dqz;
    const bool ldirty = (dd * 0.999999f <= thr);

    if (__ballot(ldirty)) {                      // wave-uniform branch
      const f32x2 QX = {qx, qx}, QY = {qy, qy}, QZ = {qz, qz};
#define FPS_UPD(t,a,b) {                                                   \
      const f32x2 dx = PX##t - QX;                                         \
      const f32x2 dy = PY##t - QY;                                         \
      const f32x2 dz = PZ##t - QZ;                                         \
      const f32x2 xx = dx * dx;                                            \
      const f32x2 yy = dy * dy;                                            \
      const f32x2 zz = dz * dz;                                            \
      const f32x2 ss = xx + yy;                                            \
      const f32x2 d2 = ss + zz;                                            \
      md##a = fminf(md##a, d2.x);                                          \
      md##b = fminf(md##b, d2.y); }
      REPP(FPS_UPD)
#undef FPS_UPD

      // lane max via max3 tree
      const float a0 = fmaxf(fmaxf(md0,  md1),  md2);
      const float a1 = fmaxf(fmaxf(md3,  md4),  md5);
      const float a2 = fmaxf(fmaxf(md6,  md7),  md8);
      const float a3 = fmaxf(fmaxf(md9,  md10), md11);
      const float a4 = fmaxf(fmaxf(md12, md13), md14);
      const float b0 = fmaxf(fmaxf(a0, a1), a2);
      const float b1 = fmaxf(fmaxf(a3, a4), md15);
      const float m  = fmaxf(b0, b1);

      // min original index among md_j == m (exact numpy tie semantics)
      unsigned c = 0xFFFFFFFFu;
#define FPS_SCAN(j) c = (md##j == m) ? (ni##j < c ? ni##j : c) : c;
      REP16(FPS_SCAN)
#undef FPS_SCAN
      u64 k = ((u64)__float_as_uint(m) << 32) | (unsigned)(N_PTS - 1 - c);

      // wave max via DPP (lane 63 ends with full wave max)
      k = kmax_dpp<0xB1,  0xf>(k);   // quad_perm [1,0,3,2]
      k = kmax_dpp<0x4E,  0xf>(k);   // quad_perm [2,3,0,1]
      k = kmax_dpp<0x141, 0xf>(k);   // row_half_mirror (8-group)
      k = kmax_dpp<0x140, 0xf>(k);   // row_mirror      (16-group)
      k = kmax_dpp<0x142, 0xa>(k);   // row_bcast15 -> rows 1,3 (32-group)
      k = kmax_dpp<0x143, 0xc>(k);   // row_bcast31 -> rows 2,3 (64-group)
      wkk = k;

      // rebuild cached chunk prune threshold (conservative margins, r9 math)
      const float u = (cr + sqrtf(m * 1.0001f)) * 1.000003f;
      thr = u * u * 1.000001f;
    }

    const int par = s & 1;
    if (lane == 63) s_wkey[par][wid] = wkk;      // lane 63 holds wave max
    __syncthreads();                             // the ONLY barrier per step
    u64 kk = s_wkey[par][lane & 15];
    kk = kmax_dpp<0xB1,  0xf>(kk);
    kk = kmax_dpp<0x4E,  0xf>(kk);
    kk = kmax_dpp<0x141, 0xf>(kk);
    kk = kmax_dpp<0x140, 0xf>(kk);               // all lanes: block max

    const int oidx = (N_PTS - 1) - (int)(unsigned)(kk & 0xFFFFFFFFu);
    const float4 wpt = coords4[oidx];            // one uniform 16B load
    qx = wpt.x; qy = wpt.y; qz = wpt.z;
    if (tid == 0) {
      float* orow = out + (size_t)s * ROWF;
      orow[0] = qx; orow[1] = qy; orow[2] = qz;
    }
  }
}

// ---------------------------------------------------------------------------
// 4) KNN top-16 (ties -> lowest index) fused with feature max-pool.
//    One wave per query; query coords read from out rows (written by fps).
// ---------------------------------------------------------------------------
__global__ __launch_bounds__(256)
void knn_pool_kernel(const float* __restrict__ x,
                     const float4* __restrict__ coords4,
                     float* __restrict__ out) {
  const int lane = threadIdx.x & 63;
  const int q = blockIdx.x * 4 + (threadIdx.x >> 6);

  const float qx = out[(size_t)q * ROWF + 0];
  const float qy = out[(size_t)q * ROWF + 1];
  const float qz = out[(size_t)q * ROWF + 2];

  u64 h[KNN];
#pragma unroll
  for (int k = 0; k < KNN; ++k) h[k] = ~0ULL;

  for (int c = lane; c < N_PTS; c += 64) {
    const float4 v = coords4[c];                 // coalesced 16B
    const float dx = v.x - qx, dy = v.y - qy, dz = v.z - qz;
    const float d2 = __fadd_rn(__fadd_rn(__fmul_rn(dx, dx), __fmul_rn(dy, dy)),
                               __fmul_rn(dz, dz));
    const u64 e = ((u64)__float_as_uint(d2) << 32) | (unsigned)c;
    if (e < h[KNN - 1]) {
#pragma unroll
      for (int k = KNN - 1; k >= 1; --k) {
        const u64 prev = h[k - 1];
        h[k] = (e < prev) ? prev : ((e < h[k]) ? e : h[k]);
      }
      h[0] = (e < h[0]) ? e : h[0];
    }
  }

  int nbr[KNN];
#pragma unroll
  for (int rr = 0; rr < KNN; ++rr) {
    u64 best = h[0];
#pragma unroll
    for (int off = 32; off; off >>= 1) {
      const u64 o = __shfl_xor(best, off);
      best = (o < best) ? o : best;
    }
    nbr[rr] = (int)(unsigned)(best & 0xffffffffULL);
    if (h[0] == best) {
#pragma unroll
      for (int k = 0; k < KNN - 1; ++k) h[k] = h[k + 1];
      h[KNN - 1] = ~0ULL;
    }
  }

  float a0 = __int_as_float(0xff800000), a1 = a0;
#pragma unroll
  for (int rr = 0; rr < KNN; ++rr) {
    const float* row = x + (size_t)nbr[rr] * ROWF + 3;
    a0 = fmaxf(a0, row[lane]);
    a1 = fmaxf(a1, row[lane + 64]);
  }
  float* orow = out + (size_t)q * ROWF + 3;
  orow[lane] = a0;
  orow[lane + 64] = a1;
}

extern "C" void kernel_launch(void* const* d_in, const int* in_sizes, int n_in,
                              void* d_out, int out_size, void* d_ws, size_t ws_size,
                              hipStream_t stream) {
  const float* x = (const float*)d_in[0];
  float* out = (float*)d_out;

  float4* coords4 = (float4*)d_ws;          // N float4 (256 KB), orig order
  float4* gP4     = coords4 + N_PTS;        // N float4 (256 KB), Morton slot-major

  hipLaunchKernelGGL(prep_kernel, dim3(64), dim3(256), 0, stream, x, coords4);
  hipLaunchKernelGGL(sort_kernel, dim3(1), dim3(1024), 0, stream, coords4, gP4);
  hipLaunchKernelGGL(fps_kernel, dim3(1), dim3(FPS_T), 0, stream,
                     coords4, gP4, out);
  hipLaunchKernelGGL(knn_pool_kernel, dim3(M_OUT / 4), dim3(256), 0, stream,
                     x, coords4, out);
}

// Round 17
// 6218.245 us; speedup vs baseline: 1.0897x; 1.0897x over previous
//
#include <hip/hip_runtime.h>

#define N_PTS 16384
#define ROWF  131        // 3 coords + 128 features
#define M_OUT 4096       // N / POOL
#define KNN   16
#define FPS_T 1024       // fps threads (16 waves)

typedef unsigned long long u64;
typedef float f32x2 __attribute__((ext_vector_type(2)));

// DPP cross-lane helpers (VALU pipe). Control constants proven r10-r16.
template <int CTRL, int ROW_MASK>
__device__ __forceinline__ float fmax_dpp(float v) {
  const int p = __builtin_amdgcn_update_dpp(__float_as_int(v), __float_as_int(v),
                                            CTRL, ROW_MASK, 0xf, false);
  return fmaxf(v, __int_as_float(p));
}
template <int CTRL, int ROW_MASK>
__device__ __forceinline__ unsigned umin_dpp(unsigned v) {
  const unsigned p = (unsigned)__builtin_amdgcn_update_dpp((int)v, (int)v,
                                            CTRL, ROW_MASK, 0xf, false);
  return v < p ? v : p;
}

// ---------------------------------------------------------------------------
// 1) Extract coords into packed float4 (x,y,z,0), original index order.
// ---------------------------------------------------------------------------
__global__ void prep_kernel(const float* __restrict__ x,
                            float4* __restrict__ coords4) {
  const int p = blockIdx.x * blockDim.x + threadIdx.x;
  if (p < N_PTS) {
    coords4[p] = make_float4(x[p * ROWF + 0], x[p * ROWF + 1],
                             x[p * ROWF + 2], 0.0f);
  }
}

// ---------------------------------------------------------------------------
// 2) FPS v15: f32 common path + winner-only deferred index resolution.
//    r15/r16 lesson: issue-bound; prune never pays (barrier waits for the
//    dirty wave). The only removable issue was the u64 key machinery
//    (~90 ops/wave/step) paid by all waves though only ~1 wave needs it.
//    Step: pk update (bitwise == numpy mul/add chain, no fma) -> max3 tree
//    -> 6-level f32 DPP wave fold -> lane63 writes s_wmax[par] -> b1 ->
//    4-level f32 DPP block fold (mm) -> SCALAR-uniform winner test
//    (readlane(wavemax,63)==readfirstlane(mm), SGPR cmp) -> winning wave
//    only: 16-elem scan (min j with md==mm; ni=tid+(j<<10), orig order) +
//    6-level u32-min DPP + lane63 writes s_arg[par] -> b2 -> 4-level u32
//    min block fold -> winner index -> uniform coords load.
//    Parity buffers: s_wmax written pre-b1/read post-b1 (2-barrier reuse
//    separation); s_arg[par^1] reset AFTER b1 (last read of that buffer
//    was before the PREVIOUS b1 -> race-free), winner writes s_arg[par]
//    between b1 and b2, read after b2.
//    Semantics: mm = max md (fmax returns operand bits); winners = waves
//    with wavemax==mm; each contributes min orig idx among md_j==mm;
//    u32-min across waves => numpy argmax-first-index. absmax 0 expected.
// ---------------------------------------------------------------------------
#define REP16R(F) F(15) F(14) F(13) F(12) F(11) F(10) F(9) F(8) \
                  F(7) F(6) F(5) F(4) F(3) F(2) F(1) F(0)
#define REPP(F) F(0,0,1) F(1,2,3) F(2,4,5) F(3,6,7) \
                F(4,8,9) F(5,10,11) F(6,12,13) F(7,14,15)

__global__
__attribute__((amdgpu_flat_work_group_size(FPS_T, FPS_T)))
__attribute__((amdgpu_waves_per_eu(4, 4)))
void fps_kernel(const float4* __restrict__ coords4, float* __restrict__ out) {
#pragma clang fp contract(off)
  __shared__ float    s_wmax[2][16];
  __shared__ unsigned s_arg[2][16];
  const int tid = threadIdx.x, lane = tid & 63, wid = tid >> 6;

#define FPS_DECL(t,a,b) f32x2 PX##t, PY##t, PZ##t; float md##a, md##b;
  REPP(FPS_DECL)
#undef FPS_DECL

#define FPS_INIT(t,a,b) {                                                  \
    const float4 va = coords4[(a << 10) + tid];                            \
    const float4 vb = coords4[(b << 10) + tid];                            \
    PX##t = (f32x2){va.x, vb.x};                                           \
    PY##t = (f32x2){va.y, vb.y};                                           \
    PZ##t = (f32x2){va.z, vb.z};                                           \
    md##a = __int_as_float(0x7f800000);                                    \
    md##b = __int_as_float(0x7f800000); }
  REPP(FPS_INIT)
#undef FPS_INIT

  if (lane == 63) { s_arg[0][wid] = 0xFFFFFFFFu; s_arg[1][wid] = 0xFFFFFFFFu; }

  const float4 q0 = coords4[0];
  float qx = q0.x, qy = q0.y, qz = q0.z;
  if (tid == 0) { out[0] = qx; out[1] = qy; out[2] = qz; }

  for (int s = 1; s < M_OUT; ++s) {
    const int par = s & 1;
    const f32x2 QX = {qx, qx}, QY = {qy, qy}, QZ = {qz, qz};

    // ---- update all 16 points (pk pairs; IEEE RTNE per half, no fma)
#define FPS_UPD(t,a,b) {                                                   \
    const f32x2 dx = PX##t - QX;                                           \
    const f32x2 dy = PY##t - QY;                                           \
    const f32x2 dz = PZ##t - QZ;                                           \
    const f32x2 xx = dx * dx;                                              \
    const f32x2 yy = dy * dy;                                              \
    const f32x2 zz = dz * dz;                                              \
    const f32x2 ss = xx + yy;                                              \
    const f32x2 d2 = ss + zz;                                              \
    md##a = fminf(md##a, d2.x);                                            \
    md##b = fminf(md##b, d2.y); }
    REPP(FPS_UPD)
#undef FPS_UPD

    // ---- lane max via max3 tree
    const float a0 = fmaxf(fmaxf(md0,  md1),  md2);
    const float a1 = fmaxf(fmaxf(md3,  md4),  md5);
    const float a2 = fmaxf(fmaxf(md6,  md7),  md8);
    const float a3 = fmaxf(fmaxf(md9,  md10), md11);
    const float a4 = fmaxf(fmaxf(md12, md13), md14);
    const float b0 = fmaxf(fmaxf(a0, a1), a2);
    const float b1 = fmaxf(fmaxf(a3, a4), md15);
    const float m  = fmaxf(b0, b1);

    // ---- wave max (f32) via DPP; lane 63 ends with full wave max
    float fm = m;
    fm = fmax_dpp<0xB1,  0xf>(fm);   // quad_perm [1,0,3,2]
    fm = fmax_dpp<0x4E,  0xf>(fm);   // quad_perm [2,3,0,1]
    fm = fmax_dpp<0x141, 0xf>(fm);   // row_half_mirror
    fm = fmax_dpp<0x140, 0xf>(fm);   // row_mirror
    fm = fmax_dpp<0x142, 0xa>(fm);   // row_bcast15 -> rows 1,3
    fm = fmax_dpp<0x143, 0xc>(fm);   // row_bcast31 -> rows 2,3

    if (lane == 63) s_wmax[par][wid] = fm;
    __syncthreads();                             // barrier 1

    // reset the arg buffer last read before the PREVIOUS b1 (race-free)
    if (lane == 63) s_arg[par ^ 1][wid] = 0xFFFFFFFFu;

    // block max of 16 wave maxes (f32, 4 DPP levels)
    float bm = s_wmax[par][lane & 15];
    bm = fmax_dpp<0xB1,  0xf>(bm);
    bm = fmax_dpp<0x4E,  0xf>(bm);
    bm = fmax_dpp<0x141, 0xf>(bm);
    bm = fmax_dpp<0x140, 0xf>(bm);               // all lanes: block max mm

    // ---- winner-only index resolution (scalar-uniform branch)
    const int mwb = __builtin_amdgcn_readlane(__float_as_int(fm), 63);
    const int mmb = __builtin_amdgcn_readfirstlane(__float_as_int(bm));
    if (mwb == mmb) {                            // uniform: ~1 wave enters
      const float mmv = __int_as_float(mmb);
      unsigned c = 0xFFFFu;
#define FPS_SCAN(j) c = (md##j == mmv) ? (unsigned)j : c;
      REP16R(FPS_SCAN)
#undef FPS_SCAN
      unsigned nic = (unsigned)tid + (c << 10);  // junk (>67M) if no match
      nic = umin_dpp<0xB1,  0xf>(nic);
      nic = umin_dpp<0x4E,  0xf>(nic);
      nic = umin_dpp<0x141, 0xf>(nic);
      nic = umin_dpp<0x140, 0xf>(nic);
      nic = umin_dpp<0x142, 0xa>(nic);
      nic = umin_dpp<0x143, 0xc>(nic);
      if (lane == 63) s_arg[par][wid] = nic;
    }
    __syncthreads();                             // barrier 2

    unsigned av = s_arg[par][lane & 15];
    av = umin_dpp<0xB1,  0xf>(av);
    av = umin_dpp<0x4E,  0xf>(av);
    av = umin_dpp<0x141, 0xf>(av);
    av = umin_dpp<0x140, 0xf>(av);               // all lanes: winner index

    const int oidx = (int)av;
    const float4 wpt = coords4[oidx];            // one uniform 16B load
    qx = wpt.x; qy = wpt.y; qz = wpt.z;
    if (tid == 0) {
      float* orow = out + (size_t)s * ROWF;
      orow[0] = qx; orow[1] = qy; orow[2] = qz;
    }
  }
}

// ---------------------------------------------------------------------------
// 3) KNN top-16 (ties -> lowest index) fused with feature max-pool.
//    One wave per query; query coords read from out rows (written by fps).
//    Packed u64 (d2_bits<<32 | idx) == lex (d2, idx).
// ---------------------------------------------------------------------------
__global__ __launch_bounds__(256)
void knn_pool_kernel(const float* __restrict__ x,
                     const float4* __restrict__ coords4,
                     float* __restrict__ out) {
  const int lane = threadIdx.x & 63;
  const int q = blockIdx.x * 4 + (threadIdx.x >> 6);

  const float qx = out[(size_t)q * ROWF + 0];
  const float qy = out[(size_t)q * ROWF + 1];
  const float qz = out[(size_t)q * ROWF + 2];

  u64 h[KNN];
#pragma unroll
  for (int k = 0; k < KNN; ++k) h[k] = ~0ULL;

  for (int c = lane; c < N_PTS; c += 64) {
    const float4 v = coords4[c];                 // coalesced 16B
    const float dx = v.x - qx, dy = v.y - qy, dz = v.z - qz;
    const float d2 = __fadd_rn(__fadd_rn(__fmul_rn(dx, dx), __fmul_rn(dy, dy)),
                               __fmul_rn(dz, dz));
    const u64 e = ((u64)__float_as_uint(d2) << 32) | (unsigned)c;
    if (e < h[KNN - 1]) {
#pragma unroll
      for (int k = KNN - 1; k >= 1; --k) {
        const u64 prev = h[k - 1];
        h[k] = (e < prev) ? prev : ((e < h[k]) ? e : h[k]);
      }
      h[0] = (e < h[0]) ? e : h[0];
    }
  }

  int nbr[KNN];
#pragma unroll
  for (int rr = 0; rr < KNN; ++rr) {
    u64 best = h[0];
#pragma unroll
    for (int off = 32; off; off >>= 1) {
      const u64 o = __shfl_xor(best, off);
      best = (o < best) ? o : best;
    }
    nbr[rr] = (int)(unsigned)(best & 0xffffffffULL);
    if (h[0] == best) {
#pragma unroll
      for (int k = 0; k < KNN - 1; ++k) h[k] = h[k + 1];
      h[KNN - 1] = ~0ULL;
    }
  }

  float a0 = __int_as_float(0xff800000), a1 = a0;
#pragma unroll
  for (int rr = 0; rr < KNN; ++rr) {
    const float* row = x + (size_t)nbr[rr] * ROWF + 3;
    a0 = fmaxf(a0, row[lane]);
    a1 = fmaxf(a1, row[lane + 64]);
  }
  float* orow = out + (size_t)q * ROWF + 3;
  orow[lane] = a0;
  orow[lane + 64] = a1;
}

extern "C" void kernel_launch(void* const* d_in, const int* in_sizes, int n_in,
                              void* d_out, int out_size, void* d_ws, size_t ws_size,
                              hipStream_t stream) {
  const float* x = (const float*)d_in[0];
  float* out = (float*)d_out;

  float4* coords4 = (float4*)d_ws;          // N float4 (256 KB)

  hipLaunchKernelGGL(prep_kernel, dim3(64), dim3(256), 0, stream, x, coords4);
  hipLaunchKernelGGL(fps_kernel, dim3(1), dim3(FPS_T), 0, stream, coords4, out);
  hipLaunchKernelGGL(knn_pool_kernel, dim3(M_OUT / 4), dim3(256), 0, stream,
                     x, coords4, out);
}

// Round 18
// 6199.194 us; speedup vs baseline: 1.0931x; 1.0031x over previous
//
#include <hip/hip_runtime.h>

#define N_PTS 16384
#define ROWF  131        // 3 coords + 128 features
#define M_OUT 4096       // N / POOL
#define KNN   16
#define FPS_T 512        // fps threads (8 waves, 2/SIMD -> 256-VGPR budget)

typedef unsigned long long u64;
typedef float f32x2 __attribute__((ext_vector_type(2)));

// DPP cross-lane helpers (VALU pipe). Control constants proven r10-r17.
template <int CTRL, int ROW_MASK>
__device__ __forceinline__ float fmax_dpp(float v) {
  const int p = __builtin_amdgcn_update_dpp(__float_as_int(v), __float_as_int(v),
                                            CTRL, ROW_MASK, 0xf, false);
  return fmaxf(v, __int_as_float(p));
}
template <int CTRL, int ROW_MASK>
__device__ __forceinline__ unsigned umin_dpp(unsigned v) {
  const unsigned p = (unsigned)__builtin_amdgcn_update_dpp((int)v, (int)v,
                                            CTRL, ROW_MASK, 0xf, false);
  return v < p ? v : p;
}

// ---------------------------------------------------------------------------
// 1) Extract coords into packed float4 (x,y,z,0), original index order.
// ---------------------------------------------------------------------------
__global__ void prep_kernel(const float* __restrict__ x,
                            float4* __restrict__ coords4) {
  const int p = blockIdx.x * blockDim.x + threadIdx.x;
  if (p < N_PTS) {
    coords4[p] = make_float4(x[p * ROWF + 0], x[p * ROWF + 1],
                             x[p * ROWF + 2], 0.0f);
  }
}

// ---------------------------------------------------------------------------
// 2) FPS v16: 512 threads x 32 points, 256-VGPR budget (waves_per_eu(2,2)).
//    r4-r17 tell: VGPR_Count 52-64 << ~110-value state, no scratch spill =>
//    RA REMATERIALIZES the loop-invariant coord loads under the 128-VGPR
//    budget (4 waves/EU) -- every step re-fetches coords from L1/L2 with
//    address/bookkeeping ops, explaining measured VALU-busy ~2x the pure
//    arithmetic. At 2 waves/EU the budget is 256: keeping all 96 coord regs
//    + 32 md resident is the cheapest allocation. Work per SIMD is conserved
//    (2 waves x 2x ops); reduce tail shrinks (8 waves, 3-level block folds).
//    Structure = r17: pk-pair update (bitwise == numpy mul/add chain, no
//    fma) -> max3 tree -> 6-level f32 DPP wave fold -> lane63 s_wmax[par]
//    -> b1 -> 3-level block fold (mm) -> scalar-uniform winner test ->
//    winning wave only: 32-elem descending scan (min j => min orig idx
//    tid+(j<<9)) + 6-level u32-min DPP -> s_arg[par] -> b2 -> 3-level u32
//    block fold -> uniform winner load. Parity buffers as r17 (race-free).
//    Exact numpy argmax-first-index semantics; absmax 0 expected.
// ---------------------------------------------------------------------------
#define REP32R(F) F(31) F(30) F(29) F(28) F(27) F(26) F(25) F(24) \
                  F(23) F(22) F(21) F(20) F(19) F(18) F(17) F(16) \
                  F(15) F(14) F(13) F(12) F(11) F(10) F(9) F(8) \
                  F(7) F(6) F(5) F(4) F(3) F(2) F(1) F(0)
#define REPP(F) F(0,0,1)   F(1,2,3)   F(2,4,5)   F(3,6,7) \
                F(4,8,9)   F(5,10,11) F(6,12,13) F(7,14,15) \
                F(8,16,17) F(9,18,19) F(10,20,21) F(11,22,23) \
                F(12,24,25) F(13,26,27) F(14,28,29) F(15,30,31)

__global__
__attribute__((amdgpu_flat_work_group_size(FPS_T, FPS_T)))
__attribute__((amdgpu_waves_per_eu(2, 2)))
void fps_kernel(const float4* __restrict__ coords4, float* __restrict__ out) {
#pragma clang fp contract(off)
  __shared__ float    s_wmax[2][8];
  __shared__ unsigned s_arg[2][8];
  const int tid = threadIdx.x, lane = tid & 63, wid = tid >> 6;

#define FPS_DECL(t,a,b) f32x2 PX##t, PY##t, PZ##t; float md##a, md##b;
  REPP(FPS_DECL)
#undef FPS_DECL

#define FPS_INIT(t,a,b) {                                                  \
    const float4 va = coords4[(a << 9) + tid];                             \
    const float4 vb = coords4[(b << 9) + tid];                             \
    PX##t = (f32x2){va.x, vb.x};                                           \
    PY##t = (f32x2){va.y, vb.y};                                           \
    PZ##t = (f32x2){va.z, vb.z};                                           \
    md##a = __int_as_float(0x7f800000);                                    \
    md##b = __int_as_float(0x7f800000); }
  REPP(FPS_INIT)
#undef FPS_INIT

  if (lane == 63) { s_arg[0][wid] = 0xFFFFFFFFu; s_arg[1][wid] = 0xFFFFFFFFu; }

  const float4 q0 = coords4[0];
  float qx = q0.x, qy = q0.y, qz = q0.z;
  if (tid == 0) { out[0] = qx; out[1] = qy; out[2] = qz; }

  for (int s = 1; s < M_OUT; ++s) {
    const int par = s & 1;
    const f32x2 QX = {qx, qx}, QY = {qy, qy}, QZ = {qz, qz};

    // ---- update all 32 points (pk pairs; IEEE RTNE per half, no fma)
#define FPS_UPD(t,a,b) {                                                   \
    const f32x2 dx = PX##t - QX;                                           \
    const f32x2 dy = PY##t - QY;                                           \
    const f32x2 dz = PZ##t - QZ;                                           \
    const f32x2 xx = dx * dx;                                              \
    const f32x2 yy = dy * dy;                                              \
    const f32x2 zz = dz * dz;                                              \
    const f32x2 ss = xx + yy;                                              \
    const f32x2 d2 = ss + zz;                                              \
    md##a = fminf(md##a, d2.x);                                            \
    md##b = fminf(md##b, d2.y); }
    REPP(FPS_UPD)
#undef FPS_UPD

    // ---- lane max over 32 via max3-friendly tree
    const float c0 = fmaxf(fmaxf(md0,  md1),  md2);
    const float c1 = fmaxf(fmaxf(md3,  md4),  md5);
    const float c2 = fmaxf(fmaxf(md6,  md7),  md8);
    const float c3 = fmaxf(fmaxf(md9,  md10), md11);
    const float c4 = fmaxf(fmaxf(md12, md13), md14);
    const float c5 = fmaxf(fmaxf(md15, md16), md17);
    const float c6 = fmaxf(fmaxf(md18, md19), md20);
    const float c7 = fmaxf(fmaxf(md21, md22), md23);
    const float c8 = fmaxf(fmaxf(md24, md25), md26);
    const float c9 = fmaxf(fmaxf(md27, md28), md29);
    const float ca = fmaxf(md30, md31);
    const float d0 = fmaxf(fmaxf(c0, c1), c2);
    const float d1 = fmaxf(fmaxf(c3, c4), c5);
    const float d2_ = fmaxf(fmaxf(c6, c7), c8);
    const float d3 = fmaxf(c9, ca);
    const float m  = fmaxf(fmaxf(d0, d1), fmaxf(d2_, d3));

    // ---- wave max (f32) via DPP; lane 63 ends with full wave max
    float fm = m;
    fm = fmax_dpp<0xB1,  0xf>(fm);   // quad_perm [1,0,3,2]
    fm = fmax_dpp<0x4E,  0xf>(fm);   // quad_perm [2,3,0,1]
    fm = fmax_dpp<0x141, 0xf>(fm);   // row_half_mirror
    fm = fmax_dpp<0x140, 0xf>(fm);   // row_mirror
    fm = fmax_dpp<0x142, 0xa>(fm);   // row_bcast15 -> rows 1,3
    fm = fmax_dpp<0x143, 0xc>(fm);   // row_bcast31 -> rows 2,3

    if (lane == 63) s_wmax[par][wid] = fm;
    __syncthreads();                             // barrier 1

    // reset the arg buffer last read before the PREVIOUS b1 (race-free)
    if (lane == 63) s_arg[par ^ 1][wid] = 0xFFFFFFFFu;

    // block max of 8 wave maxes (f32, 3 DPP levels)
    float bm = s_wmax[par][lane & 7];
    bm = fmax_dpp<0xB1,  0xf>(bm);
    bm = fmax_dpp<0x4E,  0xf>(bm);
    bm = fmax_dpp<0x141, 0xf>(bm);               // all lanes: block max mm

    // ---- winner-only index resolution (scalar-uniform branch)
    const int mwb = __builtin_amdgcn_readlane(__float_as_int(fm), 63);
    const int mmb = __builtin_amdgcn_readfirstlane(__float_as_int(bm));
    if (mwb == mmb) {                            // uniform: ~1 wave enters
      const float mmv = __int_as_float(mmb);
      unsigned c = 0xFFFFu;
#define FPS_SCAN(j) c = (md##j == mmv) ? (unsigned)j : c;
      REP32R(FPS_SCAN)
#undef FPS_SCAN
      unsigned nic = (unsigned)tid + (c << 9);   // junk (>33M) if no match
      nic = umin_dpp<0xB1,  0xf>(nic);
      nic = umin_dpp<0x4E,  0xf>(nic);
      nic = umin_dpp<0x141, 0xf>(nic);
      nic = umin_dpp<0x140, 0xf>(nic);
      nic = umin_dpp<0x142, 0xa>(nic);
      nic = umin_dpp<0x143, 0xc>(nic);
      if (lane == 63) s_arg[par][wid] = nic;
    }
    __syncthreads();                             // barrier 2

    unsigned av = s_arg[par][lane & 7];
    av = umin_dpp<0xB1,  0xf>(av);
    av = umin_dpp<0x4E,  0xf>(av);
    av = umin_dpp<0x141, 0xf>(av);               // all lanes: winner index

    const int oidx = (int)av;
    const float4 wpt = coords4[oidx];            // one uniform 16B load
    qx = wpt.x; qy = wpt.y; qz = wpt.z;
    if (tid == 0) {
      float* orow = out + (size_t)s * ROWF;
      orow[0] = qx; orow[1] = qy; orow[2] = qz;
    }
  }
}

// ---------------------------------------------------------------------------
// 3) KNN top-16 (ties -> lowest index) fused with feature max-pool.
//    One wave per query; query coords read from out rows (written by fps).
//    Packed u64 (d2_bits<<32 | idx) == lex (d2, idx).
// ---------------------------------------------------------------------------
__global__ __launch_bounds__(256)
void knn_pool_kernel(const float* __restrict__ x,
                     const float4* __restrict__ coords4,
                     float* __restrict__ out) {
  const int lane = threadIdx.x & 63;
  const int q = blockIdx.x * 4 + (threadIdx.x >> 6);

  const float qx = out[(size_t)q * ROWF + 0];
  const float qy = out[(size_t)q * ROWF + 1];
  const float qz = out[(size_t)q * ROWF + 2];

  u64 h[KNN];
#pragma unroll
  for (int k = 0; k < KNN; ++k) h[k] = ~0ULL;

  for (int c = lane; c < N_PTS; c += 64) {
    const float4 v = coords4[c];                 // coalesced 16B
    const float dx = v.x - qx, dy = v.y - qy, dz = v.z - qz;
    const float d2 = __fadd_rn(__fadd_rn(__fmul_rn(dx, dx), __fmul_rn(dy, dy)),
                               __fmul_rn(dz, dz));
    const u64 e = ((u64)__float_as_uint(d2) << 32) | (unsigned)c;
    if (e < h[KNN - 1]) {
#pragma unroll
      for (int k = KNN - 1; k >= 1; --k) {
        const u64 prev = h[k - 1];
        h[k] = (e < prev) ? prev : ((e < h[k]) ? e : h[k]);
      }
      h[0] = (e < h[0]) ? e : h[0];
    }
  }

  int nbr[KNN];
#pragma unroll
  for (int rr = 0; rr < KNN; ++rr) {
    u64 best = h[0];
#pragma unroll
    for (int off = 32; off; off >>= 1) {
      const u64 o = __shfl_xor(best, off);
      best = (o < best) ? o : best;
    }
    nbr[rr] = (int)(unsigned)(best & 0xffffffffULL);
    if (h[0] == best) {
#pragma unroll
      for (int k = 0; k < KNN - 1; ++k) h[k] = h[k + 1];
      h[KNN - 1] = ~0ULL;
    }
  }

  float a0 = __int_as_float(0xff800000), a1 = a0;
#pragma unroll
  for (int rr = 0; rr < KNN; ++rr) {
    const float* row = x + (size_t)nbr[rr] * ROWF + 3;
    a0 = fmaxf(a0, row[lane]);
    a1 = fmaxf(a1, row[lane + 64]);
  }
  float* orow = out + (size_t)q * ROWF + 3;
  orow[lane] = a0;
  orow[lane + 64] = a1;
}

extern "C" void kernel_launch(void* const* d_in, const int* in_sizes, int n_in,
                              void* d_out, int out_size, void* d_ws, size_t ws_size,
                              hipStream_t stream) {
  const float* x = (const float*)d_in[0];
  float* out = (float*)d_out;

  float4* coords4 = (float4*)d_ws;          // N float4 (256 KB)

  hipLaunchKernelGGL(prep_kernel, dim3(64), dim3(256), 0, stream, x, coords4);
  hipLaunchKernelGGL(fps_kernel, dim3(1), dim3(FPS_T), 0, stream, coords4, out);
  hipLaunchKernelGGL(knn_pool_kernel, dim3(M_OUT / 4), dim3(256), 0, stream,
                     x, coords4, out);
}